// Round 7
// baseline (155376.575 us; speedup 1.0000x reference)
//
#include <hip/hip_runtime.h>
#include <cstdint>
#include <cstddef>

typedef _Float16 half8  __attribute__((ext_vector_type(8)));
typedef float    floatx4 __attribute__((ext_vector_type(4)));
typedef unsigned int uintx4 __attribute__((ext_vector_type(4)));

#define T_STEPS 1500
#define BATCH   16
#define FDIM    440
#define FPAD    448
#define HDIM    512
#define MROWS   (T_STEPS*BATCH)   /* 24000 */
#define NGATES  1024
#define EXW     4096              /* u64 words per state snapshot (32 KB) */
#define FAST_SPIN (1 << 16)       /* per-wait budget, optimistic sc0 mode */
#define SAFE_SPIN (1 << 22)       /* per-wait budget, MALL fallback mode */

// ---------------- small utility kernels ----------------

__global__ __launch_bounds__(256) void cvt_pad(const float* __restrict__ src,
                                               _Float16* __restrict__ dst,
                                               int src_cols, int dst_cols) {
    int row = blockIdx.x;
    for (int k = threadIdx.x; k < dst_cols; k += 256) {
        float v = (k < src_cols) ? src[(size_t)row * src_cols + k] : 0.f;
        dst[(size_t)row * dst_cols + k] = (_Float16)v;
    }
}

__global__ __launch_bounds__(256) void cat2(const float* __restrict__ a,
                                            const float* __restrict__ b,
                                            float* __restrict__ dst) {
    int i = blockIdx.x * 256 + threadIdx.x;
    if (i < 1024) dst[i] = (i < 512) ? a[i] : b[i - 512];
}

// ---------------- GEMM: C[M,1024] = A[M,Kp] * B[1024,Kp]^T + bias (layer 0 gates) ----

__global__ __launch_bounds__(256) void gemm_tn(const _Float16* __restrict__ A,
                                               const _Float16* __restrict__ B,
                                               const float* __restrict__ bias,
                                               float* __restrict__ C32,
                                               _Float16* __restrict__ C16,
                                               int M, int Kp, int use_f32) {
    __shared__ _Float16 As[128 * 40];
    __shared__ _Float16 Bs[128 * 40];

    const int tid = threadIdx.x;
    const int wv = tid >> 6, l = tid & 63, q = l >> 4, c = l & 15;
    const int wr = wv >> 1, wc = wv & 1;
    const int m0 = blockIdx.y * 128, n0 = blockIdx.x * 128;

    floatx4 acc[4][4] = {};

    for (int kt = 0; kt < Kp; kt += 32) {
#pragma unroll
        for (int i = 0; i < 2; ++i) {
            int s = tid + i * 256;
            int row = s >> 2, qq = s & 3;
            uint4 va = {0u, 0u, 0u, 0u};
            int gm = m0 + row;
            if (gm < M) va = *(const uint4*)(A + (size_t)gm * Kp + kt + qq * 8);
            *(uint4*)(As + row * 40 + qq * 8) = va;
            uint4 vb = *(const uint4*)(B + (size_t)(n0 + row) * Kp + kt + qq * 8);
            *(uint4*)(Bs + row * 40 + qq * 8) = vb;
        }
        __syncthreads();

        half8 af[4], bf[4];
#pragma unroll
        for (int mi = 0; mi < 4; ++mi)
            af[mi] = *(const half8*)(As + (wr * 64 + mi * 16 + c) * 40 + q * 8);
#pragma unroll
        for (int ni = 0; ni < 4; ++ni)
            bf[ni] = *(const half8*)(Bs + (wc * 64 + ni * 16 + c) * 40 + q * 8);
#pragma unroll
        for (int mi = 0; mi < 4; ++mi)
#pragma unroll
            for (int ni = 0; ni < 4; ++ni)
                acc[mi][ni] = __builtin_amdgcn_mfma_f32_16x16x32_f16(af[mi], bf[ni], acc[mi][ni], 0, 0, 0);
        __syncthreads();
    }

#pragma unroll
    for (int ni = 0; ni < 4; ++ni) {
        int n = n0 + wc * 64 + ni * 16 + c;
        float bv = bias[n];
#pragma unroll
        for (int mi = 0; mi < 4; ++mi) {
#pragma unroll
            for (int r = 0; r < 4; ++r) {
                int gm = m0 + wr * 64 + mi * 16 + q * 4 + r;
                if (gm < M) {
                    float v = acc[mi][ni][r] + bv;
                    if (use_f32) C32[(size_t)gm * NGATES + n] = v;
                    else         C16[(size_t)gm * NGATES + n] = (_Float16)v;
                }
            }
        }
    }
}

// ---------------- exchange primitives ----------------
// DOUBLE STORE: plain store updates the writer-XCD L2 (visible to same-XCD
// sc0 polls); sc0 sc1 store writes through to MALL (fallback path always
// correct, = round-3-proven AGENT-atomic semantics). Same value both times.
// Loads: optimistic sc0 (XCD-L2); per-WAIT budget escalates to sc0 sc1
// (sticky) on exhaustion; an sc1-mode exhaustion gives up (terminate with
// diagnostics) instead of hanging.

__device__ __forceinline__ void st64(unsigned long long* p, unsigned long long v) {
    asm volatile("global_store_dwordx2 %0, %1, off\n\t"
                 "global_store_dwordx2 %0, %1, off sc0 sc1"
                 :: "v"(p), "v"(v) : "memory");
}

__device__ __forceinline__ void stage64(const unsigned long long* __restrict__ src,
                                        unsigned tag, int j, char* lds,
                                        int& sc1mode) {
    const unsigned long long* p = src + (size_t)j * 8;
    const int b  = j >> 5;            // batch
    const int ks = (j & 31) >> 1;     // k-slice
    const int q2 = (j & 1) * 2;       // q-chunk pair
    uintx4 A, B, C, D;
    int budget = sc1mode ? SAFE_SPIN : FAST_SPIN;   // PER-WAIT budget (r6 bug: was cumulative)
    for (;;) {
        if (!sc1mode) {
            asm volatile(
                "global_load_dwordx4 %0, %4, off sc0\n\t"
                "global_load_dwordx4 %1, %4, off offset:16 sc0\n\t"
                "global_load_dwordx4 %2, %4, off offset:32 sc0\n\t"
                "global_load_dwordx4 %3, %4, off offset:48 sc0\n\t"
                "s_waitcnt vmcnt(0)"
                : "=&v"(A), "=&v"(B), "=&v"(C), "=&v"(D) : "v"(p) : "memory");
        } else {
            asm volatile(
                "global_load_dwordx4 %0, %4, off sc0 sc1\n\t"
                "global_load_dwordx4 %1, %4, off offset:16 sc0 sc1\n\t"
                "global_load_dwordx4 %2, %4, off offset:32 sc0 sc1\n\t"
                "global_load_dwordx4 %3, %4, off offset:48 sc0 sc1\n\t"
                "s_waitcnt vmcnt(0)"
                : "=&v"(A), "=&v"(B), "=&v"(C), "=&v"(D) : "v"(p) : "memory");
        }
        unsigned bad = ((unsigned)A.y ^ tag) | ((unsigned)A.w ^ tag) |
                       ((unsigned)B.y ^ tag) | ((unsigned)B.w ^ tag) |
                       ((unsigned)C.y ^ tag) | ((unsigned)C.w ^ tag) |
                       ((unsigned)D.y ^ tag) | ((unsigned)D.w ^ tag);
        if (bad == 0u) break;
        if (--budget < 0) {
            if (sc1mode) break;       // truly impossible state: terminate, don't hang
            sc1mode = 1;              // sticky escalation to MALL-coherent loads
            budget = SAFE_SPIN;
        }
    }
    uint32_t* l0 = (uint32_t*)(lds + ks * 1040 + (q2 * 16 + b) * 16);
    l0[0] = A.x; l0[1] = A.z; l0[2] = B.x; l0[3] = B.z;
    uint32_t* l1 = (uint32_t*)(lds + ks * 1040 + ((q2 + 1) * 16 + b) * 16);
    l1[0] = C.x; l1[1] = C.z; l1[2] = D.x; l1[3] = D.z;
}

// ---------------- fused 2-layer persistent scan, single-XCD team ----------------
// 128 candidate WGs x 512 thr; first XCD to assemble 16 WGs runs the job
// (roles 0-7: layer-0, 64 feats each; roles 8-15: layer-1). Others exit.
// Pigeonhole (ceil(128/8)=16) + co-residency (128 WGs <= 256 CUs) => a winner
// always emerges; losers' spin terminates once the winner is published.

__global__ __launch_bounds__(512, 1) void ligru_fused(
        const float* __restrict__ gates32, const _Float16* __restrict__ gates16,
        const _Float16* __restrict__ U0z, const _Float16* __restrict__ U0h,
        const _Float16* __restrict__ U1z, const _Float16* __restrict__ U1h,
        const _Float16* __restrict__ W1z, const _Float16* __restrict__ W1h,
        unsigned int* __restrict__ sel,         // [0..7] rank ctrs, [8] winner
        unsigned long long* __restrict__ exA,   // [2][EXW] layer-0 h ring
        unsigned long long* __restrict__ exC,   // [2][EXW] layer-1 h ring
        unsigned long long* __restrict__ H1T,   // [T_STEPS][EXW] tagged layer-0 out
        const float* __restrict__ bh1, const float* __restrict__ bz1,
        float* __restrict__ out, int use_gf32) {

    __shared__ char ldsX[16 * 1040];
    __shared__ char ldsY[16 * 1040];
    __shared__ float accS[2][4][16][16];
    __shared__ int s_role;

    // ---- team selection (XCC_ID measured working on this HW: learn_hip m09) ----
    if (threadIdx.x == 0) {
        unsigned x;
        asm volatile("s_getreg_b32 %0, hwreg(HW_REG_XCC_ID)" : "=s"(x));
        x &= 7u;
        unsigned r = atomicAdd(&sel[x], 1u);
        int role = -1;
        if (r < 16u) {
            if (r == 15u) (void)atomicCAS(&sel[8], 0u, x + 1u);
            unsigned w;
            do {
                w = __hip_atomic_load(&sel[8], __ATOMIC_RELAXED, __HIP_MEMORY_SCOPE_AGENT);
            } while (w == 0u);
            if (w == x + 1u) role = (int)r;
        }
        s_role = role;
    }
    __syncthreads();
    const int role = s_role;
    if (role < 0) return;

    const int tid = threadIdx.x;
    const int l = tid & 63, wv = tid >> 6, q = l >> 4, c = l & 15;
    const int gate = wv >> 2, ti = wv & 3;           // 8 waves = 2 gates x 4 tiles
    const bool isA = (role < 8);
    const int wg = role & 7;
    const int fbase = wg * 64;

    // epilogue mapping: thread -> (batch, local feature pair)
    const int eb  = tid >> 5;
    const int fpl = tid & 31;
    const int f0  = 2 * fpl;
    const int gf  = fbase + f0;
    const int eti = f0 >> 4, efi = f0 & 15;
    const int exi = eb * 256 + (fbase >> 1) + fpl;

    int sc1mode = 0;

    if (isA) {
        // ---- layer 0 ----
        st64(exA + exi, 0ull);                       // self-init ring buf 0 (tag0|h=0)

        const _Float16* U = (gate == 0) ? U0z : U0h;
        const int urow = fbase + ti * 16 + c;
        half8 u[16];
#pragma unroll
        for (int ks = 0; ks < 16; ++ks)
            u[ks] = *(const half8*)(U + (size_t)urow * HDIM + ks * 32 + q * 8);
#pragma unroll
        for (int ks = 0; ks < 16; ++ks)
            asm volatile("" : "+v"(u[ks]));

        float h0 = 0.f, h1 = 0.f;

        float gw0[2], gw1[2], gz0[2], gz1[2];        // 2-step gate prefetch
        auto gload = [&](int t, int s) {
            const int row = t * BATCH + eb;
            if (use_gf32) {
                float2 a2 = *(const float2*)(gates32 + (size_t)row * NGATES + gf);
                float2 b2 = *(const float2*)(gates32 + (size_t)row * NGATES + 512 + gf);
                gw0[s] = a2.x; gw1[s] = a2.y; gz0[s] = b2.x; gz1[s] = b2.y;
            } else {
                union { uint32_t u; _Float16 h[2]; } ua, ub;
                ua.u = *(const uint32_t*)(gates16 + (size_t)row * NGATES + gf);
                ub.u = *(const uint32_t*)(gates16 + (size_t)row * NGATES + 512 + gf);
                gw0[s] = (float)ua.h[0]; gw1[s] = (float)ua.h[1];
                gz0[s] = (float)ub.h[0]; gz1[s] = (float)ub.h[1];
            }
        };
        gload(0, 0);
        gload(1, 1);

        for (int t = 0; t < T_STEPS; ++t) {
            stage64(exA + (size_t)(t & 1) * EXW, (unsigned)t, tid, ldsX, sc1mode);
            __syncthreads();

            floatx4 acc = {0.f, 0.f, 0.f, 0.f};
#pragma unroll
            for (int ks = 0; ks < 16; ++ks) {
                half8 a = *(const half8*)(ldsX + ks * 1040 + l * 16);
                acc = __builtin_amdgcn_mfma_f32_16x16x32_f16(a, u[ks], acc, 0, 0, 0);
            }
            *(floatx4*)&accS[gate][ti][c][q * 4] = acc;
            __syncthreads();

            float Sz0 = accS[0][eti][efi][eb],     Sh0 = accS[1][eti][efi][eb];
            float Sz1 = accS[0][eti][efi + 1][eb], Sh1 = accS[1][eti][efi + 1][eb];

            const int s = t & 1;
            float z0 = 1.f / (1.f + __expf(-(gz0[s] + Sz0)));
            float z1 = 1.f / (1.f + __expf(-(gz1[s] + Sz1)));
            float hc0 = fmaxf(0.f, gw0[s] + Sh0);
            float hc1 = fmaxf(0.f, gw1[s] + Sh1);
            h0 = z0 * h0 + (1.f - z0) * hc0;
            h1 = z1 * h1 + (1.f - z1) * hc1;

            union { _Float16 h[2]; uint32_t u; } pk;
            pk.h[0] = (_Float16)h0; pk.h[1] = (_Float16)h1;
            unsigned long long tg = ((unsigned long long)(unsigned)(t + 1) << 32) | pk.u;
            st64(exA + (size_t)((t + 1) & 1) * EXW + exi, tg);
            st64(H1T + (size_t)t * EXW + exi, tg);

            if (t + 2 < T_STEPS) gload(t + 2, s);
        }
    } else {
        // ---- layer 1 (input projection folded in) ----
        st64(exC + exi, 0ull);                       // self-init ring buf 0

        const _Float16* Wm = (gate == 0) ? W1z : W1h;
        const _Float16* Um = (gate == 0) ? U1z : U1h;
        const int urow = fbase + ti * 16 + c;
        half8 w[16], u[16];
#pragma unroll
        for (int ks = 0; ks < 16; ++ks) {
            w[ks] = *(const half8*)(Wm + (size_t)urow * HDIM + ks * 32 + q * 8);
            u[ks] = *(const half8*)(Um + (size_t)urow * HDIM + ks * 32 + q * 8);
        }
#pragma unroll
        for (int ks = 0; ks < 16; ++ks) {
            asm volatile("" : "+v"(w[ks]));
            asm volatile("" : "+v"(u[ks]));
        }

        const float bzv0 = bz1[gf], bzv1 = bz1[gf + 1];
        const float bhv0 = bh1[gf], bhv1 = bh1[gf + 1];
        float h0 = 0.f, h1 = 0.f;

        for (int t = 0; t < T_STEPS; ++t) {
            stage64(H1T + (size_t)t * EXW, (unsigned)(t + 1), tid, ldsX, sc1mode);
            stage64(exC + (size_t)(t & 1) * EXW, (unsigned)t, tid, ldsY, sc1mode);
            __syncthreads();

            floatx4 acc = {0.f, 0.f, 0.f, 0.f};
#pragma unroll
            for (int ks = 0; ks < 16; ++ks) {
                half8 a = *(const half8*)(ldsX + ks * 1040 + l * 16);
                acc = __builtin_amdgcn_mfma_f32_16x16x32_f16(a, w[ks], acc, 0, 0, 0);
            }
#pragma unroll
            for (int ks = 0; ks < 16; ++ks) {
                half8 a = *(const half8*)(ldsY + ks * 1040 + l * 16);
                acc = __builtin_amdgcn_mfma_f32_16x16x32_f16(a, u[ks], acc, 0, 0, 0);
            }
            *(floatx4*)&accS[gate][ti][c][q * 4] = acc;
            __syncthreads();

            float Sz0 = accS[0][eti][efi][eb],     Sh0 = accS[1][eti][efi][eb];
            float Sz1 = accS[0][eti][efi + 1][eb], Sh1 = accS[1][eti][efi + 1][eb];

            float z0 = 1.f / (1.f + __expf(-(bzv0 + Sz0)));
            float z1 = 1.f / (1.f + __expf(-(bzv1 + Sz1)));
            float hc0 = fmaxf(0.f, bhv0 + Sh0);
            float hc1 = fmaxf(0.f, bhv1 + Sh1);
            h0 = z0 * h0 + (1.f - z0) * hc0;
            h1 = z1 * h1 + (1.f - z1) * hc1;

            union { _Float16 h[2]; uint32_t u; } pk;
            pk.h[0] = (_Float16)h0; pk.h[1] = (_Float16)h1;
            unsigned long long tg = ((unsigned long long)(unsigned)(t + 1) << 32) | pk.u;
            st64(exC + (size_t)((t + 1) & 1) * EXW + exi, tg);

            float2 o; o.x = h0; o.y = h1;
            *(float2*)(out + (size_t)(t * BATCH + eb) * HDIM + gf) = o;
        }
    }
}

// ---------------- host ----------------

extern "C" void kernel_launch(void* const* d_in, const int* in_sizes, int n_in,
                              void* d_out, int out_size, void* d_ws, size_t ws_size,
                              hipStream_t stream) {
    const float* x   = (const float*)d_in[0];
    const float* Wh0 = (const float*)d_in[1];
    const float* bh0 = (const float*)d_in[2];
    const float* Wz0 = (const float*)d_in[3];
    const float* bz0 = (const float*)d_in[4];
    const float* Uh0 = (const float*)d_in[5];
    const float* Uz0 = (const float*)d_in[6];
    const float* Wh1 = (const float*)d_in[7];
    const float* bh1 = (const float*)d_in[8];
    const float* Wz1 = (const float*)d_in[9];
    const float* bz1 = (const float*)d_in[10];
    const float* Uh1 = (const float*)d_in[11];
    const float* Uz1 = (const float*)d_in[12];
    float* out = (float*)d_out;

    uint8_t* ws = (uint8_t*)d_ws;
    size_t off = 0;
    auto alloc = [&](size_t b) { size_t o = off; off += (b + 255) & ~(size_t)255; return o; };

    const size_t EXB  = (size_t)EXW * 8;                 // 32 KB per snapshot
    const size_t H1TB = (size_t)T_STEPS * EXW * 8;       // 48 MB tagged layer-0 outputs
    size_t o_sel  = alloc(256);
    size_t o_exA  = alloc(2 * EXB);
    size_t o_exC  = alloc(2 * EXB);
    size_t o_h1t  = alloc(H1TB);                         // poison 0xAA never matches tags 1..1500
    size_t o_U0z  = alloc((size_t)HDIM * HDIM * 2);
    size_t o_U0h  = alloc((size_t)HDIM * HDIM * 2);
    size_t o_U1z  = alloc((size_t)HDIM * HDIM * 2);
    size_t o_U1h  = alloc((size_t)HDIM * HDIM * 2);
    size_t o_W1z  = alloc((size_t)HDIM * HDIM * 2);
    size_t o_W1h  = alloc((size_t)HDIM * HDIM * 2);
    size_t o_Wc0  = alloc((size_t)NGATES * FPAD * 2);
    size_t o_b0   = alloc(1024 * 4);
    size_t o_xb   = alloc((size_t)MROWS * FPAD * 2);
    size_t o_g    = off;
    size_t need32 = off + (size_t)MROWS * NGATES * 4;
    int use_gf32 = (ws_size >= need32) ? 1 : 0;

    unsigned int* SEL = (unsigned int*)(ws + o_sel);
    unsigned long long* exA = (unsigned long long*)(ws + o_exA);
    unsigned long long* exC = (unsigned long long*)(ws + o_exC);
    unsigned long long* H1T = (unsigned long long*)(ws + o_h1t);
    _Float16* U0Z = (_Float16*)(ws + o_U0z);
    _Float16* U0H = (_Float16*)(ws + o_U0h);
    _Float16* U1Z = (_Float16*)(ws + o_U1z);
    _Float16* U1H = (_Float16*)(ws + o_U1h);
    _Float16* W1Z = (_Float16*)(ws + o_W1z);
    _Float16* W1H = (_Float16*)(ws + o_W1h);
    _Float16* WC0 = (_Float16*)(ws + o_Wc0);
    float*    B0  = (float*)(ws + o_b0);
    _Float16* XB  = (_Float16*)(ws + o_xb);
    float*    G32 = (float*)(ws + o_g);
    _Float16* G16 = (_Float16*)(ws + o_g);

    // zero selection state + rings (rings also self-initialized in-kernel)
    hipMemsetAsync(ws + o_sel, 0, 256 + 4 * EXB, stream);

    // fp32 -> fp16 conversions (with K padding for layer-0 GEMM)
    cvt_pad<<<MROWS, 256, 0, stream>>>(x, XB, FDIM, FPAD);
    cvt_pad<<<512, 256, 0, stream>>>(Wh0, WC0,              FDIM, FPAD);
    cvt_pad<<<512, 256, 0, stream>>>(Wz0, WC0 + 512 * FPAD, FDIM, FPAD);
    cvt_pad<<<512, 256, 0, stream>>>(Uz0, U0Z, HDIM, HDIM);
    cvt_pad<<<512, 256, 0, stream>>>(Uh0, U0H, HDIM, HDIM);
    cvt_pad<<<512, 256, 0, stream>>>(Uz1, U1Z, HDIM, HDIM);
    cvt_pad<<<512, 256, 0, stream>>>(Uh1, U1H, HDIM, HDIM);
    cvt_pad<<<512, 256, 0, stream>>>(Wz1, W1Z, HDIM, HDIM);
    cvt_pad<<<512, 256, 0, stream>>>(Wh1, W1H, HDIM, HDIM);
    cat2<<<4, 256, 0, stream>>>(bh0, bz0, B0);

    // layer-0 gates GEMM (layer-1 projection folded into the scan)
    dim3 gg(NGATES / 128, (MROWS + 127) / 128);
    gemm_tn<<<gg, 256, 0, stream>>>(XB, WC0, B0, G32, G16, MROWS, FPAD, use_gf32);

    // fused 2-layer scan: 128 candidates, one same-XCD 16-WG team survives
    ligru_fused<<<128, 512, 0, stream>>>(G32, G16, U0Z, U0H, U1Z, U1H, W1Z, W1H,
                                         SEL, exA, exC, H1T, bh1, bz1, out, use_gf32);

    (void)in_sizes; (void)n_in; (void)out_size;
}

// Round 8
// 5804.184 us; speedup vs baseline: 26.7698x; 26.7698x over previous
//
#include <hip/hip_runtime.h>
#include <cstdint>
#include <cstddef>

typedef _Float16 half8  __attribute__((ext_vector_type(8)));
typedef float    floatx4 __attribute__((ext_vector_type(4)));
typedef unsigned int uintx4 __attribute__((ext_vector_type(4)));

#define T_STEPS 1500
#define BATCH   16
#define FDIM    440
#define FPAD    448
#define HDIM    512
#define MROWS   (T_STEPS*BATCH)   /* 24000 */
#define NGATES  1024
#define SNAPE   8192              /* f16 elems per state snapshot (16x512) */
#define SNAPB   (SNAPE*2)         /* 16 KB */
#define POLL_BUDGET (1 << 14)

// ---------------- small utility kernels ----------------

__global__ __launch_bounds__(256) void cvt_pad(const float* __restrict__ src,
                                               _Float16* __restrict__ dst,
                                               int src_cols, int dst_cols) {
    int row = blockIdx.x;
    for (int k = threadIdx.x; k < dst_cols; k += 256) {
        float v = (k < src_cols) ? src[(size_t)row * src_cols + k] : 0.f;
        dst[(size_t)row * dst_cols + k] = (_Float16)v;
    }
}

__global__ __launch_bounds__(256) void cat2(const float* __restrict__ a,
                                            const float* __restrict__ b,
                                            float* __restrict__ dst) {
    int i = blockIdx.x * 256 + threadIdx.x;
    if (i < 1024) dst[i] = (i < 512) ? a[i] : b[i - 512];
}

// ---------------- GEMM: C[M,1024] = A[M,Kp] * B[1024,Kp]^T + bias (layer 0 gates) ----

__global__ __launch_bounds__(256) void gemm_tn(const _Float16* __restrict__ A,
                                               const _Float16* __restrict__ B,
                                               const float* __restrict__ bias,
                                               float* __restrict__ C32,
                                               _Float16* __restrict__ C16,
                                               int M, int Kp, int use_f32) {
    __shared__ _Float16 As[128 * 40];
    __shared__ _Float16 Bs[128 * 40];

    const int tid = threadIdx.x;
    const int wv = tid >> 6, l = tid & 63, q = l >> 4, c = l & 15;
    const int wr = wv >> 1, wc = wv & 1;
    const int m0 = blockIdx.y * 128, n0 = blockIdx.x * 128;

    floatx4 acc[4][4] = {};

    for (int kt = 0; kt < Kp; kt += 32) {
#pragma unroll
        for (int i = 0; i < 2; ++i) {
            int s = tid + i * 256;
            int row = s >> 2, qq = s & 3;
            uint4 va = {0u, 0u, 0u, 0u};
            int gm = m0 + row;
            if (gm < M) va = *(const uint4*)(A + (size_t)gm * Kp + kt + qq * 8);
            *(uint4*)(As + row * 40 + qq * 8) = va;
            uint4 vb = *(const uint4*)(B + (size_t)(n0 + row) * Kp + kt + qq * 8);
            *(uint4*)(Bs + row * 40 + qq * 8) = vb;
        }
        __syncthreads();

        half8 af[4], bf[4];
#pragma unroll
        for (int mi = 0; mi < 4; ++mi)
            af[mi] = *(const half8*)(As + (wr * 64 + mi * 16 + c) * 40 + q * 8);
#pragma unroll
        for (int ni = 0; ni < 4; ++ni)
            bf[ni] = *(const half8*)(Bs + (wc * 64 + ni * 16 + c) * 40 + q * 8);
#pragma unroll
        for (int mi = 0; mi < 4; ++mi)
#pragma unroll
            for (int ni = 0; ni < 4; ++ni)
                acc[mi][ni] = __builtin_amdgcn_mfma_f32_16x16x32_f16(af[mi], bf[ni], acc[mi][ni], 0, 0, 0);
        __syncthreads();
    }

#pragma unroll
    for (int ni = 0; ni < 4; ++ni) {
        int n = n0 + wc * 64 + ni * 16 + c;
        float bv = bias[n];
#pragma unroll
        for (int mi = 0; mi < 4; ++mi) {
#pragma unroll
            for (int r = 0; r < 4; ++r) {
                int gm = m0 + wr * 64 + mi * 16 + q * 4 + r;
                if (gm < M) {
                    float v = acc[mi][ni][r] + bv;
                    if (use_f32) C32[(size_t)gm * NGATES + n] = v;
                    else         C16[(size_t)gm * NGATES + n] = (_Float16)v;
                }
            }
        }
    }
}

// ---------------- MALL-coherent exchange primitives (sc0 sc1 = agent scope) ----------------

__device__ __forceinline__ void st32cc(uint32_t* p, uint32_t v) {
    asm volatile("global_store_dword %0, %1, off sc0 sc1" :: "v"(p), "v"(v) : "memory");
}
__device__ __forceinline__ void ld32B(const char* p, uintx4& A, uintx4& B) {
    asm volatile("global_load_dwordx4 %0, %2, off sc0 sc1\n\t"
                 "global_load_dwordx4 %1, %2, off offset:16 sc0 sc1\n\t"
                 "s_waitcnt vmcnt(0)"
                 : "=&v"(A), "=&v"(B) : "v"(p) : "memory");
}
__device__ __forceinline__ void ld32Bx2(const char* p1, const char* p2,
                                        uintx4& A, uintx4& B, uintx4& C, uintx4& D) {
    asm volatile("global_load_dwordx4 %0, %4, off sc0 sc1\n\t"
                 "global_load_dwordx4 %1, %4, off offset:16 sc0 sc1\n\t"
                 "global_load_dwordx4 %2, %5, off sc0 sc1\n\t"
                 "global_load_dwordx4 %3, %5, off offset:16 sc0 sc1\n\t"
                 "s_waitcnt vmcnt(0)"
                 : "=&v"(A), "=&v"(B), "=&v"(C), "=&v"(D) : "v"(p1), "v"(p2) : "memory");
}
// scatter thread j's 32B (feats [(j&31)*16, +16) of batch j>>5) into frag-major LDS
__device__ __forceinline__ void scat(char* lds, int j, uintx4 A, uintx4 B) {
    const int b = j >> 5, g = j & 31;
    const int ks = g >> 1, qp = (g & 1) * 2;
    *(uintx4*)(lds + ks * 1040 + (qp * 16 + b) * 16)       = A;
    *(uintx4*)(lds + ks * 1040 + ((qp + 1) * 16 + b) * 16) = B;
}

// ---------------- fused 2-layer persistent scan, flag-gated MALL exchange ----------------
// 16 WGs x 512 thr. WGs 0-7: layer-0 (64 feats each); WGs 8-15: layer-1.
// Per step: [1 thread polls flags w/ s_sleep] -> gated bulk read (sc0 sc1) ->
// LDS -> MFMA -> epilogue stores (sc0 sc1) -> vmcnt drain -> flag release.

__global__ __launch_bounds__(512, 1) void ligru_fused(
        const float* __restrict__ gates32, const _Float16* __restrict__ gates16,
        const _Float16* __restrict__ U0z, const _Float16* __restrict__ U0h,
        const _Float16* __restrict__ U1z, const _Float16* __restrict__ U1h,
        const _Float16* __restrict__ W1z, const _Float16* __restrict__ W1h,
        unsigned int* __restrict__ flg,     // [0..7]=layer0 steps done, [8..15]=layer1
        _Float16* __restrict__ exA,         // [2][SNAPE] layer-0 h ring
        _Float16* __restrict__ exC,         // [2][SNAPE] layer-1 h ring
        _Float16* __restrict__ H1T,         // [T_STEPS][SNAPE] layer-0 outputs
        const float* __restrict__ bh1, const float* __restrict__ bz1,
        float* __restrict__ out, int use_gf32) {

    __shared__ char ldsX[16 * 1040];
    __shared__ char ldsY[16 * 1040];
    __shared__ float accS[2][4][16][16];

    const int tid = threadIdx.x;
    const int l = tid & 63, wv = tid >> 6, q = l >> 4, c = l & 15;
    const int gate = wv >> 2, ti = wv & 3;           // 8 waves = 2 gates x 4 tiles
    const bool isA = (blockIdx.x < 8);
    const int wg = blockIdx.x & 7;
    const int fbase = wg * 64;

    const int eb  = tid >> 5;                        // batch
    const int fpl = tid & 31;
    const int f0  = 2 * fpl;
    const int gf  = fbase + f0;                      // global feature (even)
    const int eti = f0 >> 4, efi = f0 & 15;

    int dead = 0;                                    // tid0 only: poll fail-safe

    if (isA) {
        // ---- layer 0 ----
        const _Float16* U = (gate == 0) ? U0z : U0h;
        const int urow = fbase + ti * 16 + c;
        half8 u[16];
#pragma unroll
        for (int ks = 0; ks < 16; ++ks)
            u[ks] = *(const half8*)(U + (size_t)urow * HDIM + ks * 32 + q * 8);
#pragma unroll
        for (int ks = 0; ks < 16; ++ks)
            asm volatile("" : "+v"(u[ks]));

        float h0 = 0.f, h1 = 0.f;
        float gw0[2], gw1[2], gz0[2], gz1[2];        // 2-step gate prefetch
        auto gload = [&](int t, int s) {
            const int row = t * BATCH + eb;
            if (use_gf32) {
                float2 a2 = *(const float2*)(gates32 + (size_t)row * NGATES + gf);
                float2 b2 = *(const float2*)(gates32 + (size_t)row * NGATES + 512 + gf);
                gw0[s] = a2.x; gw1[s] = a2.y; gz0[s] = b2.x; gz1[s] = b2.y;
            } else {
                union { uint32_t u; _Float16 h[2]; } ua, ub;
                ua.u = *(const uint32_t*)(gates16 + (size_t)row * NGATES + gf);
                ub.u = *(const uint32_t*)(gates16 + (size_t)row * NGATES + 512 + gf);
                gw0[s] = (float)ua.h[0]; gw1[s] = (float)ua.h[1];
                gz0[s] = (float)ub.h[0]; gz1[s] = (float)ub.h[1];
            }
        };
        gload(0, 0);
        gload(1, 1);

        for (int t = 0; t < T_STEPS; ++t) {
            // gate: exA[t&1] complete == all layer-0 flags >= t
            if (tid == 0 && !dead) {
                int bud = POLL_BUDGET;
                for (;;) {
                    unsigned ok = 1u;
#pragma unroll
                    for (int i = 0; i < 8; ++i) {
                        unsigned v = __hip_atomic_load(&flg[i], __ATOMIC_RELAXED, __HIP_MEMORY_SCOPE_AGENT);
                        ok &= (v >= (unsigned)t) ? 1u : 0u;
                    }
                    if (ok) break;
                    __builtin_amdgcn_s_sleep(1);
                    if (--bud < 0) { dead = 1; break; }
                }
            }
            __syncthreads();

            uintx4 A, B;
            ld32B((const char*)(exA + (size_t)(t & 1) * SNAPE) + tid * 32, A, B);
            scat(ldsX, tid, A, B);
            __syncthreads();

            floatx4 acc = {0.f, 0.f, 0.f, 0.f};
#pragma unroll
            for (int ks = 0; ks < 16; ++ks) {
                half8 a = *(const half8*)(ldsX + ks * 1040 + l * 16);
                acc = __builtin_amdgcn_mfma_f32_16x16x32_f16(a, u[ks], acc, 0, 0, 0);
            }
            *(floatx4*)&accS[gate][ti][c][q * 4] = acc;
            __syncthreads();

            float Sz0 = accS[0][eti][efi][eb],     Sh0 = accS[1][eti][efi][eb];
            float Sz1 = accS[0][eti][efi + 1][eb], Sh1 = accS[1][eti][efi + 1][eb];

            const int s = t & 1;
            float z0 = 1.f / (1.f + __expf(-(gz0[s] + Sz0)));
            float z1 = 1.f / (1.f + __expf(-(gz1[s] + Sz1)));
            float hc0 = fmaxf(0.f, gw0[s] + Sh0);
            float hc1 = fmaxf(0.f, gw1[s] + Sh1);
            h0 = z0 * h0 + (1.f - z0) * hc0;
            h1 = z1 * h1 + (1.f - z1) * hc1;

            union { _Float16 h[2]; uint32_t u; } pk;
            pk.h[0] = (_Float16)h0; pk.h[1] = (_Float16)h1;
            st32cc((uint32_t*)(exA + (size_t)((t + 1) & 1) * SNAPE + eb * HDIM + gf), pk.u);
            st32cc((uint32_t*)(H1T + (size_t)t * SNAPE + eb * HDIM + gf), pk.u);

            if (t + 2 < T_STEPS) gload(t + 2, s);    // issue before the drain

            __builtin_amdgcn_s_waitcnt(0);           // data acked at MALL
            __syncthreads();
            if (tid == 0) st32cc(&flg[wg], (unsigned)(t + 1));   // release
        }
    } else {
        // ---- layer 1 (input projection folded in) ----
        const _Float16* Wm = (gate == 0) ? W1z : W1h;
        const _Float16* Um = (gate == 0) ? U1z : U1h;
        const int urow = fbase + ti * 16 + c;
        half8 w[16], u[16];
#pragma unroll
        for (int ks = 0; ks < 16; ++ks) {
            w[ks] = *(const half8*)(Wm + (size_t)urow * HDIM + ks * 32 + q * 8);
            u[ks] = *(const half8*)(Um + (size_t)urow * HDIM + ks * 32 + q * 8);
        }
#pragma unroll
        for (int ks = 0; ks < 16; ++ks) {
            asm volatile("" : "+v"(w[ks]));
            asm volatile("" : "+v"(u[ks]));
        }

        const float bzv0 = bz1[gf], bzv1 = bz1[gf + 1];
        const float bhv0 = bh1[gf], bhv1 = bh1[gf + 1];
        float h0 = 0.f, h1 = 0.f;

        for (int t = 0; t < T_STEPS; ++t) {
            // gate: H1T[t] (flagsA >= t+1) and exC[t&1] (flagsC >= t)
            if (tid == 0 && !dead) {
                int bud = POLL_BUDGET;
                for (;;) {
                    unsigned ok = 1u;
#pragma unroll
                    for (int i = 0; i < 8; ++i) {
                        unsigned a = __hip_atomic_load(&flg[i],     __ATOMIC_RELAXED, __HIP_MEMORY_SCOPE_AGENT);
                        unsigned czz = __hip_atomic_load(&flg[8 + i], __ATOMIC_RELAXED, __HIP_MEMORY_SCOPE_AGENT);
                        ok &= (a >= (unsigned)(t + 1)) ? 1u : 0u;
                        ok &= (czz >= (unsigned)t) ? 1u : 0u;
                    }
                    if (ok) break;
                    __builtin_amdgcn_s_sleep(1);
                    if (--bud < 0) { dead = 1; break; }
                }
            }
            __syncthreads();

            uintx4 A, B, C, D;
            ld32Bx2((const char*)(H1T + (size_t)t * SNAPE) + tid * 32,
                    (const char*)(exC + (size_t)(t & 1) * SNAPE) + tid * 32, A, B, C, D);
            scat(ldsX, tid, A, B);
            scat(ldsY, tid, C, D);
            __syncthreads();

            floatx4 acc = {0.f, 0.f, 0.f, 0.f};
#pragma unroll
            for (int ks = 0; ks < 16; ++ks) {
                half8 a = *(const half8*)(ldsX + ks * 1040 + l * 16);
                acc = __builtin_amdgcn_mfma_f32_16x16x32_f16(a, w[ks], acc, 0, 0, 0);
            }
#pragma unroll
            for (int ks = 0; ks < 16; ++ks) {
                half8 a = *(const half8*)(ldsY + ks * 1040 + l * 16);
                acc = __builtin_amdgcn_mfma_f32_16x16x32_f16(a, u[ks], acc, 0, 0, 0);
            }
            *(floatx4*)&accS[gate][ti][c][q * 4] = acc;
            __syncthreads();

            float Sz0 = accS[0][eti][efi][eb],     Sh0 = accS[1][eti][efi][eb];
            float Sz1 = accS[0][eti][efi + 1][eb], Sh1 = accS[1][eti][efi + 1][eb];

            float z0 = 1.f / (1.f + __expf(-(bzv0 + Sz0)));
            float z1 = 1.f / (1.f + __expf(-(bzv1 + Sz1)));
            float hc0 = fmaxf(0.f, bhv0 + Sh0);
            float hc1 = fmaxf(0.f, bhv1 + Sh1);
            h0 = z0 * h0 + (1.f - z0) * hc0;
            h1 = z1 * h1 + (1.f - z1) * hc1;

            union { _Float16 h[2]; uint32_t u; } pk;
            pk.h[0] = (_Float16)h0; pk.h[1] = (_Float16)h1;
            st32cc((uint32_t*)(exC + (size_t)((t + 1) & 1) * SNAPE + eb * HDIM + gf), pk.u);

            float2 o; o.x = h0; o.y = h1;
            *(float2*)(out + (size_t)(t * BATCH + eb) * HDIM + gf) = o;  // final output (plain)

            __builtin_amdgcn_s_waitcnt(0);
            __syncthreads();
            if (tid == 0) st32cc(&flg[8 + wg], (unsigned)(t + 1));
        }
    }
}

// ---------------- host ----------------

extern "C" void kernel_launch(void* const* d_in, const int* in_sizes, int n_in,
                              void* d_out, int out_size, void* d_ws, size_t ws_size,
                              hipStream_t stream) {
    const float* x   = (const float*)d_in[0];
    const float* Wh0 = (const float*)d_in[1];
    const float* bh0 = (const float*)d_in[2];
    const float* Wz0 = (const float*)d_in[3];
    const float* bz0 = (const float*)d_in[4];
    const float* Uh0 = (const float*)d_in[5];
    const float* Uz0 = (const float*)d_in[6];
    const float* Wh1 = (const float*)d_in[7];
    const float* bh1 = (const float*)d_in[8];
    const float* Wz1 = (const float*)d_in[9];
    const float* bz1 = (const float*)d_in[10];
    const float* Uh1 = (const float*)d_in[11];
    const float* Uz1 = (const float*)d_in[12];
    float* out = (float*)d_out;

    uint8_t* ws = (uint8_t*)d_ws;
    size_t off = 0;
    auto alloc = [&](size_t b) { size_t o = off; off += (b + 255) & ~(size_t)255; return o; };

    const size_t H1TB = (size_t)T_STEPS * SNAPB;         // 24 MB layer-0 outputs
    size_t o_flg  = alloc(256);                          // flg[16]
    size_t o_exA  = alloc(2 * SNAPB);
    size_t o_exC  = alloc(2 * SNAPB);
    size_t o_h1t  = alloc(H1TB);                         // flag-gated; no init needed
    size_t o_U0z  = alloc((size_t)HDIM * HDIM * 2);
    size_t o_U0h  = alloc((size_t)HDIM * HDIM * 2);
    size_t o_U1z  = alloc((size_t)HDIM * HDIM * 2);
    size_t o_U1h  = alloc((size_t)HDIM * HDIM * 2);
    size_t o_W1z  = alloc((size_t)HDIM * HDIM * 2);
    size_t o_W1h  = alloc((size_t)HDIM * HDIM * 2);
    size_t o_Wc0  = alloc((size_t)NGATES * FPAD * 2);
    size_t o_b0   = alloc(1024 * 4);
    size_t o_xb   = alloc((size_t)MROWS * FPAD * 2);
    size_t o_g    = off;
    size_t need32 = off + (size_t)MROWS * NGATES * 4;
    int use_gf32 = (ws_size >= need32) ? 1 : 0;

    unsigned int* FLG = (unsigned int*)(ws + o_flg);
    _Float16* EXA = (_Float16*)(ws + o_exA);
    _Float16* EXC = (_Float16*)(ws + o_exC);
    _Float16* H1T = (_Float16*)(ws + o_h1t);
    _Float16* U0Z = (_Float16*)(ws + o_U0z);
    _Float16* U0H = (_Float16*)(ws + o_U0h);
    _Float16* U1Z = (_Float16*)(ws + o_U1z);
    _Float16* U1H = (_Float16*)(ws + o_U1h);
    _Float16* W1Z = (_Float16*)(ws + o_W1z);
    _Float16* W1H = (_Float16*)(ws + o_W1h);
    _Float16* WC0 = (_Float16*)(ws + o_Wc0);
    float*    B0  = (float*)(ws + o_b0);
    _Float16* XB  = (_Float16*)(ws + o_xb);
    float*    G32 = (float*)(ws + o_g);
    _Float16* G16 = (_Float16*)(ws + o_g);

    // zero flags + both h rings (flg/exA/exC contiguous, 256-aligned sizes)
    hipMemsetAsync(ws + o_flg, 0, 256 + 4 * SNAPB, stream);

    // fp32 -> fp16 conversions (with K padding for layer-0 GEMM)
    cvt_pad<<<MROWS, 256, 0, stream>>>(x, XB, FDIM, FPAD);
    cvt_pad<<<512, 256, 0, stream>>>(Wh0, WC0,              FDIM, FPAD);
    cvt_pad<<<512, 256, 0, stream>>>(Wz0, WC0 + 512 * FPAD, FDIM, FPAD);
    cvt_pad<<<512, 256, 0, stream>>>(Uz0, U0Z, HDIM, HDIM);
    cvt_pad<<<512, 256, 0, stream>>>(Uh0, U0H, HDIM, HDIM);
    cvt_pad<<<512, 256, 0, stream>>>(Uz1, U1Z, HDIM, HDIM);
    cvt_pad<<<512, 256, 0, stream>>>(Uh1, U1H, HDIM, HDIM);
    cvt_pad<<<512, 256, 0, stream>>>(Wz1, W1Z, HDIM, HDIM);
    cvt_pad<<<512, 256, 0, stream>>>(Wh1, W1H, HDIM, HDIM);
    cat2<<<4, 256, 0, stream>>>(bh0, bz0, B0);

    // layer-0 gates GEMM (layer-1 projection folded into the scan)
    dim3 gg(NGATES / 128, (MROWS + 127) / 128);
    gemm_tn<<<gg, 256, 0, stream>>>(XB, WC0, B0, G32, G16, MROWS, FPAD, use_gf32);

    // fused 2-layer scan: exactly 16 WGs, flag-gated MALL exchange
    ligru_fused<<<16, 512, 0, stream>>>(G32, G16, U0Z, U0H, U1Z, U1H, W1Z, W1H,
                                        FLG, EXA, EXC, H1T, bh1, bz1, out, use_gf32);

    (void)in_sizes; (void)n_in; (void)out_size;
}